// Round 1
// baseline (102.035 us; speedup 1.0000x reference)
//
#include <hip/hip_runtime.h>
#include <hip/hip_bf16.h>

#define Bn 2048
#define Dn 512

typedef __bf16 bf16x8 __attribute__((ext_vector_type(8)));
typedef float f32x4 __attribute__((ext_vector_type(4)));

union Pack8 { uint4 u; __hip_bfloat16 h[8]; };

__global__ void zero_kernel(float* __restrict__ p, int n) {
  int i = blockIdx.x * 256 + threadIdx.x;
  if (i < n) p[i] = 0.0f;
}

// One wave per row; 4 waves per block. 8192 rows total (4 matrices x 2048).
__global__ void normalize_kernel(const float* __restrict__ in0, const float* __restrict__ in1,
                                 const float* __restrict__ in2, const float* __restrict__ in3,
                                 __hip_bfloat16* __restrict__ out) {
  int gid = blockIdx.x * 4 + (threadIdx.x >> 6);
  int lane = threadIdx.x & 63;
  int m = gid >> 11;
  const float* src = (m == 0 ? in0 : m == 1 ? in1 : m == 2 ? in2 : in3) + (size_t)(gid & 2047) * Dn;
  int k = lane * 8;
  float4 x0 = *(const float4*)(src + k);
  float4 x1 = *(const float4*)(src + k + 4);
  float v[8] = {x0.x, x0.y, x0.z, x0.w, x1.x, x1.y, x1.z, x1.w};
  float ss = 0.f;
#pragma unroll
  for (int e = 0; e < 8; e++) ss = fmaf(v[e], v[e], ss);
#pragma unroll
  for (int off = 1; off < 64; off <<= 1) ss += __shfl_xor(ss, off, 64);
  float scale = 1.0f / fmaxf(sqrtf(ss), 1e-8f);
  Pack8 pw;
#pragma unroll
  for (int e = 0; e < 8; e++) pw.h[e] = __float2bfloat16(v[e] * scale);
  *(uint4*)(out + (size_t)gid * Dn + k) = pw.u;
}

// 6 per-row dots from the normalized bf16 data: [oh, op, hp, on, hn, pn]
__global__ void dots_kernel(const __hip_bfloat16* __restrict__ nm, float* __restrict__ dd) {
  int row = blockIdx.x;
  int lane = threadIdx.x;  // 64
  int k = lane * 8;
  Pack8 po, ph, pp, pn;
  po.u = *(const uint4*)(nm + (size_t)row * Dn + k);
  ph.u = *(const uint4*)(nm + (size_t)(Bn + row) * Dn + k);
  pp.u = *(const uint4*)(nm + (size_t)(2 * Bn + row) * Dn + k);
  pn.u = *(const uint4*)(nm + (size_t)(3 * Bn + row) * Dn + k);
  float s[6] = {0, 0, 0, 0, 0, 0};
#pragma unroll
  for (int e = 0; e < 8; e++) {
    float o = __bfloat162float(po.h[e]);
    float h = __bfloat162float(ph.h[e]);
    float p = __bfloat162float(pp.h[e]);
    float n = __bfloat162float(pn.h[e]);
    s[0] = fmaf(o, h, s[0]);
    s[1] = fmaf(o, p, s[1]);
    s[2] = fmaf(h, p, s[2]);
    s[3] = fmaf(o, n, s[3]);
    s[4] = fmaf(h, n, s[4]);
    s[5] = fmaf(p, n, s[5]);
  }
#pragma unroll
  for (int off = 1; off < 64; off <<= 1) {
#pragma unroll
    for (int j = 0; j < 6; j++) s[j] += __shfl_xor(s[j], off, 64);
  }
  if (lane == 0) {
#pragma unroll
    for (int j = 0; j < 6; j++) dd[j * Bn + row] = s[j];
  }
}

// GEMM C = X * Y^T (all row-major [2048,512] bf16) with fused epilogue:
//   e = exp(10*c - 10)  (diag skipped for X==X pairs)
//   row-sums -> rs[rrow], col-sums -> rs[rcol] (cross pairs only)
// blockIdx.z selects the pair: 0:OO 1:HH 2:PP 3:OH 4:OP 5:HP
#define BM 64
#define BN 64
#define BK 32
#define LDT 40  // padded LDS row length (elems); 80B rows keep 16B alignment

__global__ __launch_bounds__(256) void gemm_rowsum_kernel(const __hip_bfloat16* __restrict__ nm,
                                                          float* __restrict__ rs) {
  __shared__ __hip_bfloat16 As[BM * LDT];
  __shared__ __hip_bfloat16 Bs[BN * LDT];
  const int pxA[6] = {0, 1, 2, 0, 0, 1};
  const int pyA[6] = {0, 1, 2, 1, 2, 2};
  const int rrowA[6] = {0, 1, 2, 3, 5, 7};
  const int rcolA[6] = {-1, -1, -1, 4, 6, 8};
  int z = blockIdx.z;
  const __hip_bfloat16* X = nm + (size_t)pxA[z] * Bn * Dn;
  const __hip_bfloat16* Y = nm + (size_t)pyA[z] * Bn * Dn;
  bool skip_diag = (z < 3);
  int by = blockIdx.y, bx = blockIdx.x;
  int tid = threadIdx.x, lane = tid & 63, wave = tid >> 6;
  int wr = wave >> 1, wc = wave & 1;
  int lrow = tid >> 2, kgrp = tid & 3;
  int rgrp = lane >> 4, c = lane & 15;

  f32x4 acc[2][2] = {};
  for (int k0 = 0; k0 < Dn; k0 += BK) {
    __syncthreads();
    *(uint4*)(As + lrow * LDT + kgrp * 8) =
        *(const uint4*)(X + (size_t)(by * BM + lrow) * Dn + k0 + kgrp * 8);
    *(uint4*)(Bs + lrow * LDT + kgrp * 8) =
        *(const uint4*)(Y + (size_t)(bx * BN + lrow) * Dn + k0 + kgrp * 8);
    __syncthreads();
    bf16x8 a[2], b[2];
#pragma unroll
    for (int mi = 0; mi < 2; mi++)
      a[mi] = *(const bf16x8*)(As + (wr * 32 + mi * 16 + c) * LDT + rgrp * 8);
#pragma unroll
    for (int ni = 0; ni < 2; ni++)
      b[ni] = *(const bf16x8*)(Bs + (wc * 32 + ni * 16 + c) * LDT + rgrp * 8);
#pragma unroll
    for (int mi = 0; mi < 2; mi++)
#pragma unroll
      for (int ni = 0; ni < 2; ni++)
        acc[mi][ni] = __builtin_amdgcn_mfma_f32_16x16x32_bf16(a[mi], b[ni], acc[mi][ni], 0, 0, 0);
  }

  // epilogue: exp + reductions
  float ev[2][2][4];
#pragma unroll
  for (int mi = 0; mi < 2; mi++)
#pragma unroll
    for (int ni = 0; ni < 2; ni++)
#pragma unroll
      for (int r = 0; r < 4; r++) {
        int grow = by * BM + wr * 32 + mi * 16 + rgrp * 4 + r;
        int gcol = bx * BN + wc * 32 + ni * 16 + c;
        float v = acc[mi][ni][r];
        ev[mi][ni][r] = (skip_diag && grow == gcol) ? 0.0f : __expf(10.0f * v - 10.0f);
      }

  float* rs_row = rs + rrowA[z] * Bn;
#pragma unroll
  for (int mi = 0; mi < 2; mi++)
#pragma unroll
    for (int r = 0; r < 4; r++) {
      float val = ev[mi][0][r] + ev[mi][1][r];
#pragma unroll
      for (int off = 1; off < 16; off <<= 1) val += __shfl_xor(val, off, 16);
      if (c == 0) atomicAdd(rs_row + by * BM + wr * 32 + mi * 16 + rgrp * 4 + r, val);
    }

  if (rcolA[z] >= 0) {
    float* rs_col = rs + rcolA[z] * Bn;
#pragma unroll
    for (int ni = 0; ni < 2; ni++) {
      float val = 0.f;
#pragma unroll
      for (int mi = 0; mi < 2; mi++)
#pragma unroll
        for (int r = 0; r < 4; r++) val += ev[mi][ni][r];
      val += __shfl_xor(val, 16, 64);
      val += __shfl_xor(val, 32, 64);
      if (lane < 16) atomicAdd(rs_col + bx * BN + wc * 32 + ni * 16 + c, val);
    }
  }
}

// rs layout: 0:OO 1:HH 2:PP 3:OH 4:HO 5:OP 6:PO 7:HP 8:PH
// dd layout: 0:oh 1:op 2:hp 3:on 4:hn 5:pn
__global__ void final_kernel(const float* __restrict__ rs, const float* __restrict__ dd,
                             float* __restrict__ out) {
  int tid = threadIdx.x;  // 256
  float l1 = 0.f, l2 = 0.f, l3 = 0.f;
  for (int i = tid; i < Bn; i += 256) {
    float doh = dd[i], dop = dd[Bn + i], dhp = dd[2 * Bn + i];
    float ea = __expf(10.0f * dd[3 * Bn + i] - 10.0f);
    float eb = __expf(10.0f * dd[4 * Bn + i] - 10.0f);
    float ec = __expf(10.0f * dd[5 * Bn + i] - 10.0f);
    float r0 = rs[i], r1 = rs[Bn + i], r2 = rs[2 * Bn + i];
    float r3 = rs[3 * Bn + i], r4 = rs[4 * Bn + i], r5 = rs[5 * Bn + i];
    float r6 = rs[6 * Bn + i], r7 = rs[7 * Bn + i], r8 = rs[8 * Bn + i];
    l1 += 20.0f + logf(r0 + r3 + ea) + logf(r4 + r1 + ea) - 20.0f * doh;
    l2 += 20.0f + logf(r0 + r5 + ea) + logf(r6 + r2 + ea) - 20.0f * dop;
    l3 += 20.0f + logf(r1 + r7 + eb + ec) + logf(r8 + r2 + eb + ec) - 20.0f * dhp;
  }
  __shared__ float red[3][256];
  red[0][tid] = l1; red[1][tid] = l2; red[2][tid] = l3;
  __syncthreads();
  for (int s = 128; s > 0; s >>= 1) {
    if (tid < s) {
      red[0][tid] += red[0][tid + s];
      red[1][tid] += red[1][tid + s];
      red[2][tid] += red[2][tid + s];
    }
    __syncthreads();
  }
  if (tid == 0) {
    out[0] = red[0][0] / 4096.0f;
    out[1] = red[1][0] / 4096.0f;
    out[2] = red[2][0] / 4096.0f;
  }
}

extern "C" void kernel_launch(void* const* d_in, const int* in_sizes, int n_in,
                              void* d_out, int out_size, void* d_ws, size_t ws_size,
                              hipStream_t stream) {
  const float* z0 = (const float*)d_in[0];
  const float* z1 = (const float*)d_in[1];
  const float* z2 = (const float*)d_in[2];
  const float* z3 = (const float*)d_in[3];
  float* out = (float*)d_out;

  __hip_bfloat16* nm = (__hip_bfloat16*)d_ws;                       // 4*2048*512 bf16 = 8 MB
  float* rs = (float*)((char*)d_ws + (size_t)4 * Bn * Dn * 2);      // 9*2048 f32
  float* dd = rs + 9 * Bn;                                          // 6*2048 f32

  hipLaunchKernelGGL(zero_kernel, dim3((9 * Bn + 255) / 256), dim3(256), 0, stream, rs, 9 * Bn);
  hipLaunchKernelGGL(normalize_kernel, dim3(2048), dim3(256), 0, stream, z0, z1, z2, z3, nm);
  hipLaunchKernelGGL(dots_kernel, dim3(2048), dim3(64), 0, stream, nm, dd);
  hipLaunchKernelGGL(gemm_rowsum_kernel, dim3(32, 32, 6), dim3(256), 0, stream, nm, rs);
  hipLaunchKernelGGL(final_kernel, dim3(1), dim3(256), 0, stream, rs, dd, out);
}

// Round 2
// 58.024 us; speedup vs baseline: 1.7585x; 1.7585x over previous
//
#include <hip/hip_runtime.h>
#include <hip/hip_bf16.h>

#define Bn 2048
#define Dn 512

typedef __bf16 bf16x8 __attribute__((ext_vector_type(8)));
typedef float f32x4 __attribute__((ext_vector_type(4)));

union Pack8 { uint4 u; __hip_bfloat16 h[8]; };

typedef __attribute__((address_space(1))) const unsigned int gas_u32;
typedef __attribute__((address_space(3))) unsigned int las_u32;

__device__ __forceinline__ void gload16(const void* g, void* l) {
  __builtin_amdgcn_global_load_lds((gas_u32*)g, (las_u32*)l, 16, 0, 0);
}

// One block per row index: wave m normalizes row `blockIdx.x` of matrix m,
// writes bf16 to nm, keeps f32 in LDS, then the block computes the 6 pairwise
// diagonal dots. Also zeroes rs (first 72 blocks).
__global__ __launch_bounds__(256) void normalize_kernel(
    const float* __restrict__ in0, const float* __restrict__ in1,
    const float* __restrict__ in2, const float* __restrict__ in3,
    __hip_bfloat16* __restrict__ nm, float* __restrict__ rs, float* __restrict__ dd) {
  __shared__ float sv[4][Dn];
  __shared__ float red[4][6];
  int row = blockIdx.x;
  int wave = threadIdx.x >> 6, lane = threadIdx.x & 63;

  int g = blockIdx.x * 256 + threadIdx.x;
  if (g < 9 * Bn) rs[g] = 0.0f;

  const float* src =
      (wave == 0 ? in0 : wave == 1 ? in1 : wave == 2 ? in2 : in3) + (size_t)row * Dn;
  int k = lane * 8;
  float4 x0 = *(const float4*)(src + k);
  float4 x1 = *(const float4*)(src + k + 4);
  float v[8] = {x0.x, x0.y, x0.z, x0.w, x1.x, x1.y, x1.z, x1.w};
  float ss = 0.f;
#pragma unroll
  for (int e = 0; e < 8; e++) ss = fmaf(v[e], v[e], ss);
#pragma unroll
  for (int off = 1; off < 64; off <<= 1) ss += __shfl_xor(ss, off, 64);
  float scale = 1.0f / fmaxf(sqrtf(ss), 1e-8f);
  Pack8 pw;
#pragma unroll
  for (int e = 0; e < 8; e++) {
    float nv = v[e] * scale;
    pw.h[e] = __float2bfloat16(nv);
    sv[wave][k + e] = nv;
  }
  *(uint4*)(nm + (size_t)(wave * Bn + row) * Dn + k) = pw.u;
  __syncthreads();

  // 6 diagonal dots: each thread covers 2 k-elements
  int t = threadIdx.x;
  float o0 = sv[0][2 * t], o1 = sv[0][2 * t + 1];
  float h0 = sv[1][2 * t], h1 = sv[1][2 * t + 1];
  float p0 = sv[2][2 * t], p1 = sv[2][2 * t + 1];
  float n0 = sv[3][2 * t], n1 = sv[3][2 * t + 1];
  float s[6];
  s[0] = fmaf(o0, h0, o1 * h1);
  s[1] = fmaf(o0, p0, o1 * p1);
  s[2] = fmaf(h0, p0, h1 * p1);
  s[3] = fmaf(o0, n0, o1 * n1);
  s[4] = fmaf(h0, n0, h1 * n1);
  s[5] = fmaf(p0, n0, p1 * n1);
#pragma unroll
  for (int off = 1; off < 64; off <<= 1) {
#pragma unroll
    for (int j = 0; j < 6; j++) s[j] += __shfl_xor(s[j], off, 64);
  }
  if (lane == 0) {
#pragma unroll
    for (int j = 0; j < 6; j++) red[wave][j] = s[j];
  }
  __syncthreads();
  if (threadIdx.x < 6) {
    int j = threadIdx.x;
    dd[j * Bn + row] = red[0][j] + red[1][j] + red[2][j] + red[3][j];
  }
}

// C = X * Y^T fused with e = exp(10c-10), row-sum and col-sum accumulation.
// 128x128 tile, BK=32, 4 waves (2x2), each wave 64x64 (4x4 fragments of 16x16x32).
// Staging via global_load_lds width=16, linear LDS layout.
// z: 0:OO 1:HH 2:PP (symmetric: only bx>=by computed, col-sums of off-diag
// blocks folded back into the row-sum array) 3:OH 4:OP 5:HP.
#define BM 128
#define BK 32

__global__ __launch_bounds__(256) void gemm_rowsum_kernel(const __hip_bfloat16* __restrict__ nm,
                                                          float* __restrict__ rs) {
  __shared__ __hip_bfloat16 As[BM * BK];
  __shared__ __hip_bfloat16 Bs[BM * BK];
  const int pxA[6] = {0, 1, 2, 0, 0, 1};
  const int pyA[6] = {0, 1, 2, 1, 2, 2};
  const int rrowA[6] = {0, 1, 2, 3, 5, 7};
  const int rcolA[6] = {0, 1, 2, 4, 6, 8};
  int z = blockIdx.z;
  int by = blockIdx.y, bx = blockIdx.x;
  bool sym = (z < 3);
  if (sym && bx < by) return;  // uniform early exit, before any barrier

  const __hip_bfloat16* X = nm + (size_t)pxA[z] * Bn * Dn;
  const __hip_bfloat16* Y = nm + (size_t)pyA[z] * Bn * Dn;
  int tid = threadIdx.x, lane = tid & 63, wave = tid >> 6;
  int wr = wave >> 1, wc = wave & 1;
  int c = lane & 15, rgrp = lane >> 4;

  // staging: thread covers global row srow (2 insts: +0 / +64), 8 elems at scol
  int srow = wave * 16 + (lane >> 2);
  int scol = (lane & 3) * 8;
  const __hip_bfloat16* gA = X + (size_t)(by * BM + srow) * Dn + scol;
  const __hip_bfloat16* gB = Y + (size_t)(bx * BM + srow) * Dn + scol;
  char* ldsA = (char*)As + wave * 1024;  // wave-uniform base; HW adds lane*16
  char* ldsB = (char*)Bs + wave * 1024;

  f32x4 acc[4][4] = {};
  for (int k0 = 0; k0 < Dn; k0 += BK) {
    __syncthreads();  // previous iter's LDS reads done before overwrite
    gload16(gA + k0, ldsA);
    gload16(gA + k0 + (size_t)64 * Dn, ldsA + 4096);
    gload16(gB + k0, ldsB);
    gload16(gB + k0 + (size_t)64 * Dn, ldsB + 4096);
    __syncthreads();  // compiler drains vmcnt before barrier -> LDS ready
    bf16x8 a[4], b[4];
#pragma unroll
    for (int mi = 0; mi < 4; mi++)
      a[mi] = *(const bf16x8*)((const char*)As + (wr * 64 + mi * 16 + c) * (BK * 2) + rgrp * 16);
#pragma unroll
    for (int ni = 0; ni < 4; ni++)
      b[ni] = *(const bf16x8*)((const char*)Bs + (wc * 64 + ni * 16 + c) * (BK * 2) + rgrp * 16);
#pragma unroll
    for (int mi = 0; mi < 4; mi++)
#pragma unroll
      for (int ni = 0; ni < 4; ni++)
        acc[mi][ni] = __builtin_amdgcn_mfma_f32_16x16x32_bf16(a[mi], b[ni], acc[mi][ni], 0, 0, 0);
  }

  // epilogue: exp in place (C/D layout: row = rgrp*4+r from A-op, col = c from B-op)
  bool skip_diag = sym && (by == bx);
#pragma unroll
  for (int mi = 0; mi < 4; mi++)
#pragma unroll
    for (int ni = 0; ni < 4; ni++)
#pragma unroll
      for (int r = 0; r < 4; r++) {
        int grow = by * BM + wr * 64 + mi * 16 + rgrp * 4 + r;
        int gcol = bx * BM + wc * 64 + ni * 16 + c;
        float e = __expf(10.0f * acc[mi][ni][r] - 10.0f);
        acc[mi][ni][r] = (skip_diag && grow == gcol) ? 0.0f : e;
      }

  float* rs_row = rs + rrowA[z] * Bn;
#pragma unroll
  for (int mi = 0; mi < 4; mi++)
#pragma unroll
    for (int r = 0; r < 4; r++) {
      float val = acc[mi][0][r] + acc[mi][1][r] + acc[mi][2][r] + acc[mi][3][r];
#pragma unroll
      for (int off = 1; off < 16; off <<= 1) val += __shfl_xor(val, off, 16);
      if (c == 0) atomicAdd(rs_row + by * BM + wr * 64 + mi * 16 + rgrp * 4 + r, val);
    }

  // col sums: cross pairs always; symmetric pairs only for off-diagonal blocks
  // (they mirror into the row-sum array)
  if (!sym || (bx != by)) {
    float* rs_col = sym ? rs_row : rs + rcolA[z] * Bn;
#pragma unroll
    for (int ni = 0; ni < 4; ni++) {
      float val = 0.f;
#pragma unroll
      for (int mi = 0; mi < 4; mi++)
#pragma unroll
        for (int r = 0; r < 4; r++) val += acc[mi][ni][r];
      val += __shfl_xor(val, 16, 64);
      val += __shfl_xor(val, 32, 64);
      if (lane < 16) atomicAdd(rs_col + bx * BM + wc * 64 + ni * 16 + c, val);
    }
  }
}

// rs layout: 0:OO 1:HH 2:PP 3:OH 4:HO 5:OP 6:PO 7:HP 8:PH
// dd layout: 0:oh 1:op 2:hp 3:on 4:hn 5:pn
__global__ void final_kernel(const float* __restrict__ rs, const float* __restrict__ dd,
                             float* __restrict__ out) {
  int tid = threadIdx.x;  // 256
  float l1 = 0.f, l2 = 0.f, l3 = 0.f;
  for (int i = tid; i < Bn; i += 256) {
    float doh = dd[i], dop = dd[Bn + i], dhp = dd[2 * Bn + i];
    float ea = __expf(10.0f * dd[3 * Bn + i] - 10.0f);
    float eb = __expf(10.0f * dd[4 * Bn + i] - 10.0f);
    float ec = __expf(10.0f * dd[5 * Bn + i] - 10.0f);
    float r0 = rs[i], r1 = rs[Bn + i], r2 = rs[2 * Bn + i];
    float r3 = rs[3 * Bn + i], r4 = rs[4 * Bn + i], r5 = rs[5 * Bn + i];
    float r6 = rs[6 * Bn + i], r7 = rs[7 * Bn + i], r8 = rs[8 * Bn + i];
    l1 += 20.0f + logf(r0 + r3 + ea) + logf(r4 + r1 + ea) - 20.0f * doh;
    l2 += 20.0f + logf(r0 + r5 + ea) + logf(r6 + r2 + ea) - 20.0f * dop;
    l3 += 20.0f + logf(r1 + r7 + eb + ec) + logf(r8 + r2 + eb + ec) - 20.0f * dhp;
  }
  __shared__ float red[3][256];
  red[0][tid] = l1; red[1][tid] = l2; red[2][tid] = l3;
  __syncthreads();
  for (int s = 128; s > 0; s >>= 1) {
    if (tid < s) {
      red[0][tid] += red[0][tid + s];
      red[1][tid] += red[1][tid + s];
      red[2][tid] += red[2][tid + s];
    }
    __syncthreads();
  }
  if (tid == 0) {
    out[0] = red[0][0] / 4096.0f;
    out[1] = red[1][0] / 4096.0f;
    out[2] = red[2][0] / 4096.0f;
  }
}

extern "C" void kernel_launch(void* const* d_in, const int* in_sizes, int n_in,
                              void* d_out, int out_size, void* d_ws, size_t ws_size,
                              hipStream_t stream) {
  const float* z0 = (const float*)d_in[0];
  const float* z1 = (const float*)d_in[1];
  const float* z2 = (const float*)d_in[2];
  const float* z3 = (const float*)d_in[3];
  float* out = (float*)d_out;

  __hip_bfloat16* nm = (__hip_bfloat16*)d_ws;                   // 4*2048*512 bf16 = 8 MB
  float* rs = (float*)((char*)d_ws + (size_t)4 * Bn * Dn * 2);  // 9*2048 f32
  float* dd = rs + 9 * Bn;                                      // 6*2048 f32

  hipLaunchKernelGGL(normalize_kernel, dim3(2048), dim3(256), 0, stream,
                     z0, z1, z2, z3, nm, rs, dd);
  hipLaunchKernelGGL(gemm_rowsum_kernel, dim3(16, 16, 6), dim3(256), 0, stream, nm, rs);
  hipLaunchKernelGGL(final_kernel, dim3(1), dim3(256), 0, stream, rs, dd, out);
}